// Round 4
// baseline (259.645 us; speedup 1.0000x reference)
//
#include <hip/hip_runtime.h>
#include <hip/hip_bf16.h>

#define N_NODES 100000
#define N_EDGES 1600000
#define D 128
#define N_TILES 6250             // N_NODES/16
#define NB 512                   // buckets
#define RPB 196                  // rows per bucket (512*196 = 100352 >= N_NODES)
#define BCAP 3584                // slab capacity: mean 3136 + 8 sigma (R9-validated margin)
#define SA_EDGES 3125            // edges per scatterA WG (512*3125 = 1.6M exact)
#define CAP 16                   // LDS staging depth per bucket (R0-proven config)
#define NCH 13                   // col chunks of 8192 rows (2MB bf16 slice, fits XCD L2)
#define BPC 208                  // bins per chunk = 16 waves * 13 slots
#define KEYS 2704                // NCH*BPC
#define KEYP 2752                // padded to 64*43 for single-wave scan

typedef __bf16 bf16x8 __attribute__((ext_vector_type(8)));
typedef float  f32x4  __attribute__((ext_vector_type(4)));
typedef float  f32x2  __attribute__((ext_vector_type(2)));
typedef int    i32x2  __attribute__((ext_vector_type(2)));

// ---- K1: W transpose (fp32 -> bf16 WT) + zero bucket cursors ----
__global__ __launch_bounds__(256) void prep_kernel(const float* __restrict__ W,
                                                   __bf16* __restrict__ WT,
                                                   int* __restrict__ bucketCnt) {
    int t = blockIdx.x * 256 + threadIdx.x;   // 16384 threads
    int k = t >> 7, n = t & 127;
    WT[n * D + k] = (__bf16)W[t];
    if (t < NB) bucketCnt[t] = 0;
}

// ---- K2: GEMM h = bf16(x) @ bf16(W) (verified since R6) ----
__global__ __launch_bounds__(256) void gemm_kernel(
        const float* __restrict__ x,
        const __bf16* __restrict__ WT,
        __bf16* __restrict__ h) {
    __shared__ __bf16 lsm[4][16][144];
    const int wave = threadIdx.x >> 6;
    const int lane = threadIdx.x & 63;
    const int tile = blockIdx.x * 4 + wave;
    if (tile >= N_TILES) return;
    const int m = lane & 15, quad = lane >> 4;
    const float* xp = x + (size_t)(tile * 16 + m) * D + quad * 8;

    f32x4 acc[8];
#pragma unroll
    for (int ct = 0; ct < 8; ++ct) acc[ct] = (f32x4)(0.0f);
#pragma unroll
    for (int kk = 0; kk < 4; ++kk) {
        f32x4 a0 = *(const f32x4*)(xp + kk * 32);
        f32x4 a1 = *(const f32x4*)(xp + kk * 32 + 4);
        bf16x8 a;
#pragma unroll
        for (int j = 0; j < 4; ++j) { a[j] = (__bf16)a0[j]; a[j + 4] = (__bf16)a1[j]; }
#pragma unroll
        for (int ct = 0; ct < 8; ++ct) {
            bf16x8 b = *(const bf16x8*)(WT + (size_t)(ct * 16 + m) * D + kk * 32 + quad * 8);
            acc[ct] = __builtin_amdgcn_mfma_f32_16x16x32_bf16(a, b, acc[ct], 0, 0, 0);
        }
    }
#pragma unroll
    for (int ct = 0; ct < 8; ++ct)
#pragma unroll
        for (int r = 0; r < 4; ++r)
            lsm[wave][quad * 4 + r][ct * 16 + m] = (__bf16)acc[ct][r];
#pragma unroll
    for (int i = 0; i < 4; ++i) {
        int rl = i * 4 + quad;
        bf16x8 vv = *(const bf16x8*)&lsm[wave][rl][m * 8];
        *(bf16x8*)(h + (size_t)(tile * 16 + rl) * D + m * 8) = vv;
    }
}

// ---- K3: LDS-staged scatter into fixed-capacity bucket slabs (R0-proven) ----
// pack = (localRow<<17) | col, val as bits; claims via global per-bucket cursor
__global__ __launch_bounds__(256) void scatterA_kernel(
        const int* __restrict__ rows, const int* __restrict__ cols,
        const float* __restrict__ vals,
        int* __restrict__ bucketCnt, i32x2* __restrict__ svcA) {
    __shared__ i32x2 buf[NB][CAP];   // 64 KB
    __shared__ int   cnt[NB];        // 2 KB
    for (int t = threadIdx.x; t < NB; t += 256) cnt[t] = 0;
    __syncthreads();
    const int base = blockIdx.x * SA_EDGES;
    for (int it = 0; it < 13; ++it) {
        int idx = it * 256 + threadIdx.x;
        if (idx < SA_EDGES) {
            int e = base + idx;
            int r = rows[e];
            int b = r / RPB;                  // magic-mul division by 196
            int local = r - b * RPB;
            i32x2 pk;
            pk[0] = (local << 17) | cols[e];
            pk[1] = __float_as_int(vals[e]);
            int p = atomicAdd(&cnt[b], 1);
            if (p < CAP) buf[b][p] = pk;
            else {                             // rare overflow: direct claim
                int g = atomicAdd(&bucketCnt[b], 1);
                if (g < BCAP) svcA[(size_t)b * BCAP + g] = pk;
            }
        }
    }
    __syncthreads();
    for (int t = threadIdx.x; t < NB; t += 256) {
        int n = min(cnt[t], CAP);
        if (n > 0) {
            int g = atomicAdd(&bucketCnt[t], n);
            i32x2* dst = svcA + (size_t)t * BCAP;
            for (int i = 0; i < n; ++i)
                if (g + i < BCAP) dst[g + i] = buf[t][i];   // contiguous run
        }
    }
}

// ---- K4: chunked sort (wave-contiguous key) + TWO-PASS segsum + relu ----
// key = chunk*208 + wave*13 + slot (row = slot*16 + wave). Two row-pass
// sweep: pass A = slots 0..6, pass B = slots 7..12. Live accumulators are
// 7 named f32x2 (14 VGPR) -> fits the 64-VGPR cap of (1024,8) with NO
// scratch spill (R2/R3 lesson: 26 live acc regs spilled at this bound).
// Each pass's bins per (wave,chunk) are contiguous -> carried cursor.
__device__ __forceinline__ f32x2 bf2f(unsigned u) {
    f32x2 r;
    r[0] = __int_as_float(u << 16);
    r[1] = __int_as_float(u & 0xffff0000u);
    return r;
}

__device__ __forceinline__ int sortkey(unsigned u) {
    // u = (localRow<<17) | col ; chunk = col>>13 (0..12)
    int rl = (int)(u >> 17);
    int c  = (int)((u >> 13) & 15u);
    return c * BPC + (rl & 15) * 13 + (rl >> 4);
}

__global__ __launch_bounds__(1024, 8) void sortsum_kernel(
        const __bf16* __restrict__ h, const int* __restrict__ bucketCnt,
        const i32x2* __restrict__ svcA, float* __restrict__ out) {
    __shared__ i32x2 lbuf[BCAP];     // 28672 B
    __shared__ int   lhist[KEYP];    // 11008 B
    __shared__ int   send[KEYP];     // inclusive scan (bin ends)
    __shared__ int   lcur[KEYP];     // scatter cursors (bin starts, mutated)
    const int b   = blockIdx.x;
    const int tid = threadIdx.x;
    const int n   = min(bucketCnt[b], BCAP);
    const i32x2* win = svcA + (size_t)b * BCAP;

    for (int t = tid; t < KEYP; t += 1024) lhist[t] = 0;
    __syncthreads();

    // load window into registers (<=4 recs/thread) + LDS histogram over keys
    i32x2 rec0, rec1, rec2, rec3;
    const int i0 = tid, i1 = tid + 1024, i2 = tid + 2048, i3 = tid + 3072;
    if (i0 < n) { rec0 = win[i0]; atomicAdd(&lhist[sortkey((unsigned)rec0[0])], 1); }
    if (i1 < n) { rec1 = win[i1]; atomicAdd(&lhist[sortkey((unsigned)rec1[0])], 1); }
    if (i2 < n) { rec2 = win[i2]; atomicAdd(&lhist[sortkey((unsigned)rec2[0])], 1); }
    if (i3 < n) { rec3 = win[i3]; atomicAdd(&lhist[sortkey((unsigned)rec3[0])], 1); }
    __syncthreads();

    // single-wave scan over 2752 bins: 43 contiguous bins per lane + shuffle scan
    if (tid < 64) {
        const int base = tid * 43;
        int run = 0;
        for (int j = 0; j < 43; ++j) run += lhist[base + j];
        int s = run;
#pragma unroll
        for (int d = 1; d < 64; d <<= 1) {
            int t2 = __shfl_up(s, d, 64);
            if (tid >= d) s += t2;
        }
        int acc = s - run;               // exclusive prefix of this 43-bin group
        for (int j = 0; j < 43; ++j) {
            int hv = lhist[base + j];
            lcur[base + j] = acc;
            acc += hv;
            send[base + j] = acc;
        }
    }
    __syncthreads();

    // scatter registers into (chunk, wave, slot)-sorted LDS
    if (i0 < n) { lbuf[atomicAdd(&lcur[sortkey((unsigned)rec0[0])], 1)] = rec0; }
    if (i1 < n) { lbuf[atomicAdd(&lcur[sortkey((unsigned)rec1[0])], 1)] = rec1; }
    if (i2 < n) { lbuf[atomicAdd(&lcur[sortkey((unsigned)rec2[0])], 1)] = rec2; }
    if (i3 < n) { lbuf[atomicAdd(&lcur[sortkey((unsigned)rec3[0])], 1)] = rec3; }
    __syncthreads();

    const int wave = tid >> 6;
    const int lane = tid & 63;
    const char* hb = (const char*)h;
    const unsigned lo4 = (unsigned)lane * 4u;

#define ROW(J, AJ)                                                              \
    {                                                                           \
        const int e_ = send[kb + (J)];                                          \
        for (; i + 1 < e_; i += 2) {                                            \
            i32x2 q0 = lbuf[i], q1 = lbuf[i + 1];                               \
            unsigned u0 = *(const unsigned*)(hb + ((((unsigned)q0[0]) & 0x1FFFFu) << 8) + lo4); \
            unsigned u1 = *(const unsigned*)(hb + ((((unsigned)q1[0]) & 0x1FFFFu) << 8) + lo4); \
            AJ += bf2f(u0) * __int_as_float(q0[1]);                             \
            AJ += bf2f(u1) * __int_as_float(q1[1]);                             \
        }                                                                       \
        if (i < e_) {                                                           \
            i32x2 q0 = lbuf[i]; ++i;                                            \
            unsigned u0 = *(const unsigned*)(hb + ((((unsigned)q0[0]) & 0x1FFFFu) << 8) + lo4); \
            AJ += bf2f(u0) * __int_as_float(q0[1]);                             \
        }                                                                       \
    }
#define STORE(J, AJ)                                                            \
    {                                                                           \
        const int rl = (J) * 16 + wave;                                         \
        const int gr = b * RPB + rl;                                            \
        if (rl < RPB && gr < N_NODES) {                                         \
            f32x2 o;                                                            \
            o[0] = fmaxf(AJ[0], 0.0f);                                          \
            o[1] = fmaxf(AJ[1], 0.0f);                                          \
            __builtin_nontemporal_store(o, (f32x2*)(out + (size_t)gr * D + lane * 2)); \
        }                                                                       \
    }

    // ---- pass A: slots 0..6 (rows 0..111) ----
    {
        f32x2 A0 = (f32x2)(0.0f), A1 = (f32x2)(0.0f), A2 = (f32x2)(0.0f);
        f32x2 A3 = (f32x2)(0.0f), A4 = (f32x2)(0.0f), A5 = (f32x2)(0.0f);
        f32x2 A6 = (f32x2)(0.0f);
        for (int c = 0; c < NCH; ++c) {
            const int kb = c * BPC + wave * 13;
            int i = kb ? send[kb - 1] : 0;
            ROW(0, A0) ROW(1, A1) ROW(2, A2) ROW(3, A3)
            ROW(4, A4) ROW(5, A5) ROW(6, A6)
        }
        STORE(0, A0) STORE(1, A1) STORE(2, A2) STORE(3, A3)
        STORE(4, A4) STORE(5, A5) STORE(6, A6)
    }

    // ---- pass B: slots 7..12 (rows 112..195) ----
    {
        f32x2 B0 = (f32x2)(0.0f), B1 = (f32x2)(0.0f), B2 = (f32x2)(0.0f);
        f32x2 B3 = (f32x2)(0.0f), B4 = (f32x2)(0.0f), B5 = (f32x2)(0.0f);
        for (int c = 0; c < NCH; ++c) {
            const int kb = c * BPC + wave * 13;
            int i = send[kb + 6];
            ROW(7, B0) ROW(8, B1) ROW(9, B2) ROW(10, B3)
            ROW(11, B4) ROW(12, B5)
        }
        STORE(7, B0) STORE(8, B1) STORE(9, B2) STORE(10, B3)
        STORE(11, B4) STORE(12, B5)
    }
#undef ROW
#undef STORE
}

extern "C" void kernel_launch(void* const* d_in, const int* in_sizes, int n_in,
                              void* d_out, int out_size, void* d_ws, size_t ws_size,
                              hipStream_t stream) {
    const float* x    = (const float*)d_in[0];
    const float* w    = (const float*)d_in[1];
    const float* vals = (const float*)d_in[2];
    const int*   rows = (const int*)d_in[3];
    const int*   cols = (const int*)d_in[4];
    float*       out  = (float*)d_out;

    // ---- workspace (~40.3 MB) ----
    char* p = (char*)d_ws;
    __bf16* h         = (__bf16*)p;  p += (size_t)N_NODES * D * 2;          // 25.6 MB
    __bf16* WT        = (__bf16*)p;  p += (size_t)D * D * 2;                // 32 KB
    int*    bucketCnt = (int*)p;     p += 4096;                             // NB ints
    i32x2*  svcA      = (i32x2*)p;   p += (size_t)NB * BCAP * 8;            // 14.7 MB

    prep_kernel<<<64, 256, 0, stream>>>(w, WT, bucketCnt);
    gemm_kernel<<<(N_TILES + 3) / 4, 256, 0, stream>>>(x, WT, h);
    scatterA_kernel<<<NB, 256, 0, stream>>>(rows, cols, vals, bucketCnt, svcA);
    sortsum_kernel<<<NB, 1024, 0, stream>>>(h, bucketCnt, svcA, out);
}

// Round 5
// 228.464 us; speedup vs baseline: 1.1365x; 1.1365x over previous
//
#include <hip/hip_runtime.h>
#include <hip/hip_bf16.h>

#define N_NODES 100000
#define N_EDGES 1600000
#define D 128
#define N_TILES 6250             // N_NODES/16
#define NB 512                   // buckets
#define RPB 196                  // rows per bucket (512*196 = 100352 >= N_NODES)
#define BCAP 3584                // slab capacity: mean 3136 + 8 sigma
#define SA_EDGES 3125            // edges per scatter WG (512*3125 = 1.6M exact)
#define CAP 12                   // LDS staging depth per bucket (union LDS 50KB -> 3 blk/CU;
                                 // lambda=6.1 -> ~0.5% overflow to direct-claim path)
#define GEMM_BLKS 1563           // ceil(6250/4)
#define FUSED_BLKS 2084          // 521 groups of 4: 3 gemm + 1 scatter per group

typedef __bf16 bf16x8 __attribute__((ext_vector_type(8)));
typedef float  f32x4  __attribute__((ext_vector_type(4)));
typedef float  f32x2  __attribute__((ext_vector_type(2)));
typedef int    i32x2  __attribute__((ext_vector_type(2)));

// ---- K1: W transpose (fp32 -> bf16 WT) + zero bucket cursors ----
__global__ __launch_bounds__(256) void prep_kernel(const float* __restrict__ W,
                                                   __bf16* __restrict__ WT,
                                                   int* __restrict__ bucketCnt) {
    int t = blockIdx.x * 256 + threadIdx.x;   // 16384 threads
    int k = t >> 7, n = t & 127;
    WT[n * D + k] = (__bf16)W[t];
    if (t < NB) bucketCnt[t] = 0;
}

// ---- K2: FUSED gemm + scatter. Roles interleaved 3:1 so every CU holds a
// mix: gemm blocks (MFMA + HBM reads) overlap scatter blocks (LDS atomics +
// scattered writes). Union LDS = 50KB (scatter) vs 18KB (gemm) -> 3 blk/CU.
__global__ __launch_bounds__(256) void fused_kernel(
        const float* __restrict__ x,
        const __bf16* __restrict__ WT,
        __bf16* __restrict__ h,
        const int* __restrict__ rows, const int* __restrict__ cols,
        const float* __restrict__ vals,
        int* __restrict__ bucketCnt, i32x2* __restrict__ svcA) {
    __shared__ __align__(16) char smem[NB * CAP * 8 + NB * 4];   // 51200 B
    const int bid = blockIdx.x;
    const int g4 = bid >> 2, r = bid & 3;

    if (r == 3) {
        // ---------------- scatter role (R0-proven logic, CAP=12) ----------------
        const int sb = g4;                       // 0..520; use 512
        if (sb >= NB) return;
        i32x2 (*buf)[CAP] = (i32x2 (*)[CAP])smem;
        int*  cnt = (int*)(smem + (size_t)NB * CAP * 8);
        for (int t = threadIdx.x; t < NB; t += 256) cnt[t] = 0;
        __syncthreads();
        const int base = sb * SA_EDGES;
        for (int it = 0; it < 13; ++it) {        // 13*256 = 3328 >= 3125
            int idx = it * 256 + threadIdx.x;
            if (idx < SA_EDGES) {
                int e = base + idx;
                int rr = rows[e];
                int b = rr / RPB;                // magic-mul division by 196
                int local = rr - b * RPB;
                i32x2 pk;
                pk[0] = (local << 17) | cols[e];
                pk[1] = __float_as_int(vals[e]);
                int p = atomicAdd(&cnt[b], 1);
                if (p < CAP) buf[b][p] = pk;
                else {                           // ~0.5%: direct claim
                    int g = atomicAdd(&bucketCnt[b], 1);
                    if (g < BCAP) svcA[(size_t)b * BCAP + g] = pk;
                }
            }
        }
        __syncthreads();
        for (int t = threadIdx.x; t < NB; t += 256) {
            int n = min(cnt[t], CAP);
            if (n > 0) {
                int g = atomicAdd(&bucketCnt[t], n);
                i32x2* dst = svcA + (size_t)t * BCAP;
                for (int i = 0; i < n; ++i)
                    if (g + i < BCAP) dst[g + i] = buf[t][i];   // contiguous run
            }
        }
    } else {
        // ---------------- gemm role (verified since prev-session R6) ----------------
        const int gid = g4 * 3 + r;              // 0..1562, each exactly once
        __bf16 (*lsm)[16][144] = (__bf16 (*)[16][144])smem;
        const int wave = threadIdx.x >> 6;
        const int lane = threadIdx.x & 63;
        const int tile = gid * 4 + wave;
        if (tile >= N_TILES) return;
        const int m = lane & 15, quad = lane >> 4;
        const float* xp = x + (size_t)(tile * 16 + m) * D + quad * 8;

        f32x4 acc[8];
#pragma unroll
        for (int ct = 0; ct < 8; ++ct) acc[ct] = (f32x4)(0.0f);
#pragma unroll
        for (int kk = 0; kk < 4; ++kk) {
            f32x4 a0 = *(const f32x4*)(xp + kk * 32);
            f32x4 a1 = *(const f32x4*)(xp + kk * 32 + 4);
            bf16x8 a;
#pragma unroll
            for (int j = 0; j < 4; ++j) { a[j] = (__bf16)a0[j]; a[j + 4] = (__bf16)a1[j]; }
#pragma unroll
            for (int ct = 0; ct < 8; ++ct) {
                bf16x8 b = *(const bf16x8*)(WT + (size_t)(ct * 16 + m) * D + kk * 32 + quad * 8);
                acc[ct] = __builtin_amdgcn_mfma_f32_16x16x32_bf16(a, b, acc[ct], 0, 0, 0);
            }
        }
#pragma unroll
        for (int ct = 0; ct < 8; ++ct)
#pragma unroll
            for (int rr = 0; rr < 4; ++rr)
                lsm[wave][quad * 4 + rr][ct * 16 + m] = (__bf16)acc[ct][rr];
#pragma unroll
        for (int i = 0; i < 4; ++i) {
            int rl = i * 4 + quad;
            bf16x8 vv = *(const bf16x8*)&lsm[wave][rl][m * 8];
            *(bf16x8*)(h + (size_t)(tile * 16 + rl) * D + m * 8) = vv;
        }
    }
}

// ---- K3: fused local sort (hist + single-wave shuffle scan) + segsum + relu
// EXACT R1 code (proven 64.5us, VGPR 28). Row-sort only, 8-deep gather
// pipeline, register accumulators.
__device__ __forceinline__ f32x2 bf2f(unsigned u) {
    f32x2 r;
    r[0] = __int_as_float(u << 16);
    r[1] = __int_as_float(u & 0xffff0000u);
    return r;
}

__global__ __launch_bounds__(1024, 8) void sortsum_kernel(
        const __bf16* __restrict__ h, const int* __restrict__ bucketCnt,
        const i32x2* __restrict__ svcA, float* __restrict__ out) {
    __shared__ i32x2 lbuf[BCAP];     // 28 KB
    __shared__ int   lhist[256];
    __shared__ int   send[256];      // inclusive scan (row ends)
    __shared__ int   lcur[256];      // scatter cursors (row starts, mutated)
    const int b   = blockIdx.x;
    const int tid = threadIdx.x;
    const int n   = min(bucketCnt[b], BCAP);
    const i32x2* win = svcA + (size_t)b * BCAP;

    if (tid < 256) lhist[tid] = 0;
    __syncthreads();

    // load window into registers (<=4 recs/thread) + LDS histogram
    i32x2 rec0, rec1, rec2, rec3;
    const int i0 = tid, i1 = tid + 1024, i2 = tid + 2048, i3 = tid + 3072;
    if (i0 < n) { rec0 = win[i0]; atomicAdd(&lhist[((unsigned)rec0[0]) >> 17], 1); }
    if (i1 < n) { rec1 = win[i1]; atomicAdd(&lhist[((unsigned)rec1[0]) >> 17], 1); }
    if (i2 < n) { rec2 = win[i2]; atomicAdd(&lhist[((unsigned)rec2[0]) >> 17], 1); }
    if (i3 < n) { rec3 = win[i3]; atomicAdd(&lhist[((unsigned)rec3[0]) >> 17], 1); }
    __syncthreads();

    // single-wave scan: wave 0, 4 consecutive bins per lane + shuffle scan
    if (tid < 64) {
        int b0 = lhist[tid * 4 + 0], b1 = lhist[tid * 4 + 1];
        int b2 = lhist[tid * 4 + 2], b3 = lhist[tid * 4 + 3];
        int p0 = b0, p1 = p0 + b1, p2 = p1 + b2, p3 = p2 + b3;
        int s = p3;
#pragma unroll
        for (int d = 1; d < 64; d <<= 1) {
            int t2 = __shfl_up(s, d, 64);
            if (tid >= d) s += t2;
        }
        int ex = s - p3;                 // exclusive prefix of this 4-bin group
        send[tid * 4 + 0] = ex + p0;
        send[tid * 4 + 1] = ex + p1;
        send[tid * 4 + 2] = ex + p2;
        send[tid * 4 + 3] = ex + p3;
        lcur[tid * 4 + 0] = ex;
        lcur[tid * 4 + 1] = ex + p0;
        lcur[tid * 4 + 2] = ex + p1;
        lcur[tid * 4 + 3] = ex + p2;
    }
    __syncthreads();

    // scatter registers into row-sorted LDS
    if (i0 < n) { int rl = ((unsigned)rec0[0]) >> 17; lbuf[atomicAdd(&lcur[rl], 1)] = rec0; }
    if (i1 < n) { int rl = ((unsigned)rec1[0]) >> 17; lbuf[atomicAdd(&lcur[rl], 1)] = rec1; }
    if (i2 < n) { int rl = ((unsigned)rec2[0]) >> 17; lbuf[atomicAdd(&lcur[rl], 1)] = rec2; }
    if (i3 < n) { int rl = ((unsigned)rec3[0]) >> 17; lbuf[atomicAdd(&lcur[rl], 1)] = rec3; }
    __syncthreads();

    // per-wave register-accumulator segsum, 8-deep gather pipeline
    const int wave = tid >> 6;
    const int lane = tid & 63;
    const char* hb = (const char*)h;
    const unsigned lo4 = (unsigned)lane * 4u;
    for (int rl = wave; rl < RPB; rl += 16) {
        int gr = b * RPB + rl;
        if (gr >= N_NODES) break;
        int s = rl ? send[rl - 1] : 0;
        int e = send[rl];

        f32x2 acc0 = (f32x2)(0.0f), acc1 = (f32x2)(0.0f);
        f32x2 acc2 = (f32x2)(0.0f), acc3 = (f32x2)(0.0f);
        int i = s;
        for (; i + 7 < e; i += 8) {
            i32x2 r0 = lbuf[i],     r1 = lbuf[i + 1], r2 = lbuf[i + 2], r3 = lbuf[i + 3];
            i32x2 r4 = lbuf[i + 4], r5 = lbuf[i + 5], r6 = lbuf[i + 6], r7 = lbuf[i + 7];
            unsigned o0 = (((unsigned)r0[0] & 0x1FFFFu) << 8) + lo4;
            unsigned o1 = (((unsigned)r1[0] & 0x1FFFFu) << 8) + lo4;
            unsigned o2 = (((unsigned)r2[0] & 0x1FFFFu) << 8) + lo4;
            unsigned o3 = (((unsigned)r3[0] & 0x1FFFFu) << 8) + lo4;
            unsigned o4 = (((unsigned)r4[0] & 0x1FFFFu) << 8) + lo4;
            unsigned o5 = (((unsigned)r5[0] & 0x1FFFFu) << 8) + lo4;
            unsigned o6 = (((unsigned)r6[0] & 0x1FFFFu) << 8) + lo4;
            unsigned o7 = (((unsigned)r7[0] & 0x1FFFFu) << 8) + lo4;
            unsigned u0 = *(const unsigned*)(hb + o0);
            unsigned u1 = *(const unsigned*)(hb + o1);
            unsigned u2 = *(const unsigned*)(hb + o2);
            unsigned u3 = *(const unsigned*)(hb + o3);
            unsigned u4 = *(const unsigned*)(hb + o4);
            unsigned u5 = *(const unsigned*)(hb + o5);
            unsigned u6 = *(const unsigned*)(hb + o6);
            unsigned u7 = *(const unsigned*)(hb + o7);
            acc0 += bf2f(u0) * __int_as_float(r0[1]);
            acc1 += bf2f(u1) * __int_as_float(r1[1]);
            acc2 += bf2f(u2) * __int_as_float(r2[1]);
            acc3 += bf2f(u3) * __int_as_float(r3[1]);
            acc0 += bf2f(u4) * __int_as_float(r4[1]);
            acc1 += bf2f(u5) * __int_as_float(r5[1]);
            acc2 += bf2f(u6) * __int_as_float(r6[1]);
            acc3 += bf2f(u7) * __int_as_float(r7[1]);
        }
        for (; i + 3 < e; i += 4) {
            i32x2 r0 = lbuf[i], r1 = lbuf[i + 1], r2 = lbuf[i + 2], r3 = lbuf[i + 3];
            unsigned o0 = (((unsigned)r0[0] & 0x1FFFFu) << 8) + lo4;
            unsigned o1 = (((unsigned)r1[0] & 0x1FFFFu) << 8) + lo4;
            unsigned o2 = (((unsigned)r2[0] & 0x1FFFFu) << 8) + lo4;
            unsigned o3 = (((unsigned)r3[0] & 0x1FFFFu) << 8) + lo4;
            unsigned u0 = *(const unsigned*)(hb + o0);
            unsigned u1 = *(const unsigned*)(hb + o1);
            unsigned u2 = *(const unsigned*)(hb + o2);
            unsigned u3 = *(const unsigned*)(hb + o3);
            acc0 += bf2f(u0) * __int_as_float(r0[1]);
            acc1 += bf2f(u1) * __int_as_float(r1[1]);
            acc2 += bf2f(u2) * __int_as_float(r2[1]);
            acc3 += bf2f(u3) * __int_as_float(r3[1]);
        }
        for (; i < e; ++i) {
            i32x2 r0 = lbuf[i];
            unsigned o0 = (((unsigned)r0[0] & 0x1FFFFu) << 8) + lo4;
            unsigned u0 = *(const unsigned*)(hb + o0);
            acc0 += bf2f(u0) * __int_as_float(r0[1]);
        }

        f32x2 t01 = acc0 + acc1, t23 = acc2 + acc3;
        f32x2 tt = t01 + t23;
        f32x2 o;
        o[0] = fmaxf(tt[0], 0.0f);
        o[1] = fmaxf(tt[1], 0.0f);
        __builtin_nontemporal_store(o, (f32x2*)(out + (size_t)gr * D + lane * 2));
    }
}

extern "C" void kernel_launch(void* const* d_in, const int* in_sizes, int n_in,
                              void* d_out, int out_size, void* d_ws, size_t ws_size,
                              hipStream_t stream) {
    const float* x    = (const float*)d_in[0];
    const float* w    = (const float*)d_in[1];
    const float* vals = (const float*)d_in[2];
    const int*   rows = (const int*)d_in[3];
    const int*   cols = (const int*)d_in[4];
    float*       out  = (float*)d_out;

    // ---- workspace (~40.3 MB) ----
    char* p = (char*)d_ws;
    __bf16* h         = (__bf16*)p;  p += (size_t)N_NODES * D * 2;          // 25.6 MB
    __bf16* WT        = (__bf16*)p;  p += (size_t)D * D * 2;                // 32 KB
    int*    bucketCnt = (int*)p;     p += 4096;                             // NB ints
    i32x2*  svcA      = (i32x2*)p;   p += (size_t)NB * BCAP * 8;            // 14.7 MB

    prep_kernel<<<64, 256, 0, stream>>>(w, WT, bucketCnt);
    fused_kernel<<<FUSED_BLKS, 256, 0, stream>>>(x, WT, h, rows, cols, vals,
                                                 bucketCnt, svcA);
    sortsum_kernel<<<NB, 1024, 0, stream>>>(h, bucketCnt, svcA, out);
}

// Round 6
// 224.344 us; speedup vs baseline: 1.1574x; 1.0184x over previous
//
#include <hip/hip_runtime.h>
#include <hip/hip_bf16.h>

#define N_NODES 100000
#define N_EDGES 1600000
#define D 128
#define N_TILES 6250             // N_NODES/16
#define NB 512                   // buckets
#define RPB 196                  // rows per bucket (512*196 = 100352 >= N_NODES)
#define BCAP 3584                // slab capacity: mean 3136 + 8 sigma
#define SA_BLKS 1024             // scatter blocks (halved work -> halved tail)
#define SA_EDGES 1563            // edges per scatter block (1024*1563 = 1600512 >= 1.6M)
#define CAP 8                    // staging depth: lambda=3.05 -> ~0.1% overflow to direct path
#define FUSED_BLKS 2605          // 521 groups of 5: 3 gemm + 2 scatter

typedef __bf16 bf16x8 __attribute__((ext_vector_type(8)));
typedef float  f32x4  __attribute__((ext_vector_type(4)));
typedef float  f32x2  __attribute__((ext_vector_type(2)));
typedef int    i32x2  __attribute__((ext_vector_type(2)));

// ---- K1: W transpose (fp32 -> bf16 WT) + zero bucket cursors ----
__global__ __launch_bounds__(256) void prep_kernel(const float* __restrict__ W,
                                                   __bf16* __restrict__ WT,
                                                   int* __restrict__ bucketCnt) {
    int t = blockIdx.x * 256 + threadIdx.x;   // 16384 threads
    int k = t >> 7, n = t & 127;
    WT[n * D + k] = (__bf16)W[t];
    if (t < NB) bucketCnt[t] = 0;
}

// ---- K2: FUSED gemm + scatter, 3:2 interleave, 34.8KB union LDS ----
// 4 blocks/CU resident (vs 3 at R5's 51.2KB): gemm (MFMA + HBM reads)
// overlaps scatter (LDS atomics + scattered writes); smaller scatter blocks
// halve the low-occupancy tail.
__global__ __launch_bounds__(256) void fused_kernel(
        const float* __restrict__ x,
        const __bf16* __restrict__ WT,
        __bf16* __restrict__ h,
        const int* __restrict__ rows, const int* __restrict__ cols,
        const float* __restrict__ vals,
        int* __restrict__ bucketCnt, i32x2* __restrict__ svcA) {
    __shared__ __align__(16) char smem[NB * CAP * 8 + NB * 4];   // 34816 B
    const int bid = blockIdx.x;
    const int g5 = bid / 5, r = bid % 5;

    if (r >= 3) {
        // ---------------- scatter role (CAP=8, 1563 edges/block) ----------------
        const int sb = g5 * 2 + (r - 3);          // 0..1041; use 1024
        if (sb >= SA_BLKS) return;
        i32x2 (*buf)[CAP] = (i32x2 (*)[CAP])smem;
        int*  cnt = (int*)(smem + (size_t)NB * CAP * 8);
        for (int t = threadIdx.x; t < NB; t += 256) cnt[t] = 0;
        __syncthreads();
        const int base = sb * SA_EDGES;
        for (int it = 0; it < 7; ++it) {          // 7*256 = 1792 >= 1563
            int idx = it * 256 + threadIdx.x;
            if (idx < SA_EDGES) {
                int e = base + idx;
                if (e < N_EDGES) {
                    int rr = rows[e];
                    int b = rr / RPB;             // magic-mul division by 196
                    int local = rr - b * RPB;
                    i32x2 pk;
                    pk[0] = (local << 17) | cols[e];
                    pk[1] = __float_as_int(vals[e]);
                    int p = atomicAdd(&cnt[b], 1);
                    if (p < CAP) buf[b][p] = pk;
                    else {                        // ~0.1%: direct claim
                        int g = atomicAdd(&bucketCnt[b], 1);
                        if (g < BCAP) svcA[(size_t)b * BCAP + g] = pk;
                    }
                }
            }
        }
        __syncthreads();
        for (int t = threadIdx.x; t < NB; t += 256) {
            int n = min(cnt[t], CAP);
            if (n > 0) {
                int g = atomicAdd(&bucketCnt[t], n);
                i32x2* dst = svcA + (size_t)t * BCAP;
                for (int i = 0; i < n; ++i)
                    if (g + i < BCAP) dst[g + i] = buf[t][i];   // contiguous run
            }
        }
    } else {
        // ---------------- gemm role (verified) ----------------
        const int gid = g5 * 3 + r;               // 0..1562, each exactly once
        __bf16 (*lsm)[16][144] = (__bf16 (*)[16][144])smem;
        const int wave = threadIdx.x >> 6;
        const int lane = threadIdx.x & 63;
        const int tile = gid * 4 + wave;
        if (tile >= N_TILES) return;
        const int m = lane & 15, quad = lane >> 4;
        const float* xp = x + (size_t)(tile * 16 + m) * D + quad * 8;

        f32x4 acc[8];
#pragma unroll
        for (int ct = 0; ct < 8; ++ct) acc[ct] = (f32x4)(0.0f);
#pragma unroll
        for (int kk = 0; kk < 4; ++kk) {
            f32x4 a0 = *(const f32x4*)(xp + kk * 32);
            f32x4 a1 = *(const f32x4*)(xp + kk * 32 + 4);
            bf16x8 a;
#pragma unroll
            for (int j = 0; j < 4; ++j) { a[j] = (__bf16)a0[j]; a[j + 4] = (__bf16)a1[j]; }
#pragma unroll
            for (int ct = 0; ct < 8; ++ct) {
                bf16x8 b = *(const bf16x8*)(WT + (size_t)(ct * 16 + m) * D + kk * 32 + quad * 8);
                acc[ct] = __builtin_amdgcn_mfma_f32_16x16x32_bf16(a, b, acc[ct], 0, 0, 0);
            }
        }
#pragma unroll
        for (int ct = 0; ct < 8; ++ct)
#pragma unroll
            for (int rr = 0; rr < 4; ++rr)
                lsm[wave][quad * 4 + rr][ct * 16 + m] = (__bf16)acc[ct][rr];
#pragma unroll
        for (int i = 0; i < 4; ++i) {
            int rl = i * 4 + quad;
            bf16x8 vv = *(const bf16x8*)&lsm[wave][rl][m * 8];
            *(bf16x8*)(h + (size_t)(tile * 16 + rl) * D + m * 8) = vv;
        }
    }
}

// ---- K3: fused local sort (hist + single-wave shuffle scan) + segsum + relu
// EXACT R1 code (proven 64.5us, ~6.3 TB/s delivered = fabric ceiling).
__device__ __forceinline__ f32x2 bf2f(unsigned u) {
    f32x2 r;
    r[0] = __int_as_float(u << 16);
    r[1] = __int_as_float(u & 0xffff0000u);
    return r;
}

__global__ __launch_bounds__(1024, 8) void sortsum_kernel(
        const __bf16* __restrict__ h, const int* __restrict__ bucketCnt,
        const i32x2* __restrict__ svcA, float* __restrict__ out) {
    __shared__ i32x2 lbuf[BCAP];     // 28 KB
    __shared__ int   lhist[256];
    __shared__ int   send[256];      // inclusive scan (row ends)
    __shared__ int   lcur[256];      // scatter cursors (row starts, mutated)
    const int b   = blockIdx.x;
    const int tid = threadIdx.x;
    const int n   = min(bucketCnt[b], BCAP);
    const i32x2* win = svcA + (size_t)b * BCAP;

    if (tid < 256) lhist[tid] = 0;
    __syncthreads();

    // load window into registers (<=4 recs/thread) + LDS histogram
    i32x2 rec0, rec1, rec2, rec3;
    const int i0 = tid, i1 = tid + 1024, i2 = tid + 2048, i3 = tid + 3072;
    if (i0 < n) { rec0 = win[i0]; atomicAdd(&lhist[((unsigned)rec0[0]) >> 17], 1); }
    if (i1 < n) { rec1 = win[i1]; atomicAdd(&lhist[((unsigned)rec1[0]) >> 17], 1); }
    if (i2 < n) { rec2 = win[i2]; atomicAdd(&lhist[((unsigned)rec2[0]) >> 17], 1); }
    if (i3 < n) { rec3 = win[i3]; atomicAdd(&lhist[((unsigned)rec3[0]) >> 17], 1); }
    __syncthreads();

    // single-wave scan: wave 0, 4 consecutive bins per lane + shuffle scan
    if (tid < 64) {
        int b0 = lhist[tid * 4 + 0], b1 = lhist[tid * 4 + 1];
        int b2 = lhist[tid * 4 + 2], b3 = lhist[tid * 4 + 3];
        int p0 = b0, p1 = p0 + b1, p2 = p1 + b2, p3 = p2 + b3;
        int s = p3;
#pragma unroll
        for (int d = 1; d < 64; d <<= 1) {
            int t2 = __shfl_up(s, d, 64);
            if (tid >= d) s += t2;
        }
        int ex = s - p3;                 // exclusive prefix of this 4-bin group
        send[tid * 4 + 0] = ex + p0;
        send[tid * 4 + 1] = ex + p1;
        send[tid * 4 + 2] = ex + p2;
        send[tid * 4 + 3] = ex + p3;
        lcur[tid * 4 + 0] = ex;
        lcur[tid * 4 + 1] = ex + p0;
        lcur[tid * 4 + 2] = ex + p1;
        lcur[tid * 4 + 3] = ex + p2;
    }
    __syncthreads();

    // scatter registers into row-sorted LDS
    if (i0 < n) { int rl = ((unsigned)rec0[0]) >> 17; lbuf[atomicAdd(&lcur[rl], 1)] = rec0; }
    if (i1 < n) { int rl = ((unsigned)rec1[0]) >> 17; lbuf[atomicAdd(&lcur[rl], 1)] = rec1; }
    if (i2 < n) { int rl = ((unsigned)rec2[0]) >> 17; lbuf[atomicAdd(&lcur[rl], 1)] = rec2; }
    if (i3 < n) { int rl = ((unsigned)rec3[0]) >> 17; lbuf[atomicAdd(&lcur[rl], 1)] = rec3; }
    __syncthreads();

    // per-wave register-accumulator segsum, 8-deep gather pipeline
    const int wave = tid >> 6;
    const int lane = tid & 63;
    const char* hb = (const char*)h;
    const unsigned lo4 = (unsigned)lane * 4u;
    for (int rl = wave; rl < RPB; rl += 16) {
        int gr = b * RPB + rl;
        if (gr >= N_NODES) break;
        int s = rl ? send[rl - 1] : 0;
        int e = send[rl];

        f32x2 acc0 = (f32x2)(0.0f), acc1 = (f32x2)(0.0f);
        f32x2 acc2 = (f32x2)(0.0f), acc3 = (f32x2)(0.0f);
        int i = s;
        for (; i + 7 < e; i += 8) {
            i32x2 r0 = lbuf[i],     r1 = lbuf[i + 1], r2 = lbuf[i + 2], r3 = lbuf[i + 3];
            i32x2 r4 = lbuf[i + 4], r5 = lbuf[i + 5], r6 = lbuf[i + 6], r7 = lbuf[i + 7];
            unsigned o0 = (((unsigned)r0[0] & 0x1FFFFu) << 8) + lo4;
            unsigned o1 = (((unsigned)r1[0] & 0x1FFFFu) << 8) + lo4;
            unsigned o2 = (((unsigned)r2[0] & 0x1FFFFu) << 8) + lo4;
            unsigned o3 = (((unsigned)r3[0] & 0x1FFFFu) << 8) + lo4;
            unsigned o4 = (((unsigned)r4[0] & 0x1FFFFu) << 8) + lo4;
            unsigned o5 = (((unsigned)r5[0] & 0x1FFFFu) << 8) + lo4;
            unsigned o6 = (((unsigned)r6[0] & 0x1FFFFu) << 8) + lo4;
            unsigned o7 = (((unsigned)r7[0] & 0x1FFFFu) << 8) + lo4;
            unsigned u0 = *(const unsigned*)(hb + o0);
            unsigned u1 = *(const unsigned*)(hb + o1);
            unsigned u2 = *(const unsigned*)(hb + o2);
            unsigned u3 = *(const unsigned*)(hb + o3);
            unsigned u4 = *(const unsigned*)(hb + o4);
            unsigned u5 = *(const unsigned*)(hb + o5);
            unsigned u6 = *(const unsigned*)(hb + o6);
            unsigned u7 = *(const unsigned*)(hb + o7);
            acc0 += bf2f(u0) * __int_as_float(r0[1]);
            acc1 += bf2f(u1) * __int_as_float(r1[1]);
            acc2 += bf2f(u2) * __int_as_float(r2[1]);
            acc3 += bf2f(u3) * __int_as_float(r3[1]);
            acc0 += bf2f(u4) * __int_as_float(r4[1]);
            acc1 += bf2f(u5) * __int_as_float(r5[1]);
            acc2 += bf2f(u6) * __int_as_float(r6[1]);
            acc3 += bf2f(u7) * __int_as_float(r7[1]);
        }
        for (; i + 3 < e; i += 4) {
            i32x2 r0 = lbuf[i], r1 = lbuf[i + 1], r2 = lbuf[i + 2], r3 = lbuf[i + 3];
            unsigned o0 = (((unsigned)r0[0] & 0x1FFFFu) << 8) + lo4;
            unsigned o1 = (((unsigned)r1[0] & 0x1FFFFu) << 8) + lo4;
            unsigned o2 = (((unsigned)r2[0] & 0x1FFFFu) << 8) + lo4;
            unsigned o3 = (((unsigned)r3[0] & 0x1FFFFu) << 8) + lo4;
            unsigned u0 = *(const unsigned*)(hb + o0);
            unsigned u1 = *(const unsigned*)(hb + o1);
            unsigned u2 = *(const unsigned*)(hb + o2);
            unsigned u3 = *(const unsigned*)(hb + o3);
            acc0 += bf2f(u0) * __int_as_float(r0[1]);
            acc1 += bf2f(u1) * __int_as_float(r1[1]);
            acc2 += bf2f(u2) * __int_as_float(r2[1]);
            acc3 += bf2f(u3) * __int_as_float(r3[1]);
        }
        for (; i < e; ++i) {
            i32x2 r0 = lbuf[i];
            unsigned o0 = (((unsigned)r0[0] & 0x1FFFFu) << 8) + lo4;
            unsigned u0 = *(const unsigned*)(hb + o0);
            acc0 += bf2f(u0) * __int_as_float(r0[1]);
        }

        f32x2 t01 = acc0 + acc1, t23 = acc2 + acc3;
        f32x2 tt = t01 + t23;
        f32x2 o;
        o[0] = fmaxf(tt[0], 0.0f);
        o[1] = fmaxf(tt[1], 0.0f);
        __builtin_nontemporal_store(o, (f32x2*)(out + (size_t)gr * D + lane * 2));
    }
}

extern "C" void kernel_launch(void* const* d_in, const int* in_sizes, int n_in,
                              void* d_out, int out_size, void* d_ws, size_t ws_size,
                              hipStream_t stream) {
    const float* x    = (const float*)d_in[0];
    const float* w    = (const float*)d_in[1];
    const float* vals = (const float*)d_in[2];
    const int*   rows = (const int*)d_in[3];
    const int*   cols = (const int*)d_in[4];
    float*       out  = (float*)d_out;

    // ---- workspace (~40.3 MB) ----
    char* p = (char*)d_ws;
    __bf16* h         = (__bf16*)p;  p += (size_t)N_NODES * D * 2;          // 25.6 MB
    __bf16* WT        = (__bf16*)p;  p += (size_t)D * D * 2;                // 32 KB
    int*    bucketCnt = (int*)p;     p += 4096;                             // NB ints
    i32x2*  svcA      = (i32x2*)p;   p += (size_t)NB * BCAP * 8;            // 14.7 MB

    prep_kernel<<<64, 256, 0, stream>>>(w, WT, bucketCnt);
    fused_kernel<<<FUSED_BLKS, 256, 0, stream>>>(x, WT, h, rows, cols, vals,
                                                 bucketCnt, svcA);
    sortsum_kernel<<<NB, 1024, 0, stream>>>(h, bucketCnt, svcA, out);
}

// Round 7
// 220.450 us; speedup vs baseline: 1.1778x; 1.0177x over previous
//
#include <hip/hip_runtime.h>
#include <hip/hip_bf16.h>

#define N_NODES 100000
#define N_EDGES 1600000
#define D 128
#define N_TILES 6250             // N_NODES/16
#define NB 512                   // buckets
#define RPB 196                  // rows per bucket (512*196 = 100352 >= N_NODES)
#define BCAP 3584                // slab capacity: mean 3136 + 8 sigma
#define SB_BLKS 256              // scatterB blocks: 1 per CU, zero tail
#define SB_EDGES 6250            // 256*6250 = 1.6M exact

typedef __bf16 bf16x8 __attribute__((ext_vector_type(8)));
typedef float  f32x4  __attribute__((ext_vector_type(4)));
typedef float  f32x2  __attribute__((ext_vector_type(2)));
typedef int    i32x2  __attribute__((ext_vector_type(2)));

// ---- K1: W transpose (fp32 -> bf16 WT) + zero bucket cursors ----
__global__ __launch_bounds__(256) void prep_kernel(const float* __restrict__ W,
                                                   __bf16* __restrict__ WT,
                                                   int* __restrict__ bucketCnt) {
    int t = blockIdx.x * 256 + threadIdx.x;   // 16384 threads
    int k = t >> 7, n = t & 127;
    WT[n * D + k] = (__bf16)W[t];
    if (t < NB) bucketCnt[t] = 0;
}

// ---- K2: GEMM h = bf16(x) @ bf16(W) (verified; standalone for counters) ----
__global__ __launch_bounds__(256) void gemm_kernel(
        const float* __restrict__ x,
        const __bf16* __restrict__ WT,
        __bf16* __restrict__ h) {
    __shared__ __bf16 lsm[4][16][144];
    const int wave = threadIdx.x >> 6;
    const int lane = threadIdx.x & 63;
    const int tile = blockIdx.x * 4 + wave;
    if (tile >= N_TILES) return;
    const int m = lane & 15, quad = lane >> 4;
    const float* xp = x + (size_t)(tile * 16 + m) * D + quad * 8;

    f32x4 acc[8];
#pragma unroll
    for (int ct = 0; ct < 8; ++ct) acc[ct] = (f32x4)(0.0f);
#pragma unroll
    for (int kk = 0; kk < 4; ++kk) {
        f32x4 a0 = *(const f32x4*)(xp + kk * 32);
        f32x4 a1 = *(const f32x4*)(xp + kk * 32 + 4);
        bf16x8 a;
#pragma unroll
        for (int j = 0; j < 4; ++j) { a[j] = (__bf16)a0[j]; a[j + 4] = (__bf16)a1[j]; }
#pragma unroll
        for (int ct = 0; ct < 8; ++ct) {
            bf16x8 b = *(const bf16x8*)(WT + (size_t)(ct * 16 + m) * D + kk * 32 + quad * 8);
            acc[ct] = __builtin_amdgcn_mfma_f32_16x16x32_bf16(a, b, acc[ct], 0, 0, 0);
        }
    }
#pragma unroll
    for (int ct = 0; ct < 8; ++ct)
#pragma unroll
        for (int r = 0; r < 4; ++r)
            lsm[wave][quad * 4 + r][ct * 16 + m] = (__bf16)acc[ct][r];
#pragma unroll
    for (int i = 0; i < 4; ++i) {
        int rl = i * 4 + quad;
        bf16x8 vv = *(const bf16x8*)&lsm[wave][rl][m * 8];
        *(bf16x8*)(h + (size_t)(tile * 16 + rl) * D + m * 8) = vv;
    }
}

// ---- K3: scatterB — exact LDS counting sort, no overflow path ----
// 256 blocks x 1024 threads x 6250 edges. Records in 7 named registers;
// 512-bin hist + single-wave scan + LDS scatter (sortsum-proven pattern);
// drain = 1 far-atomic per (block,bucket), 512 concurrent claims/block,
// runs of ~12 records (~96B) per store burst.
__global__ __launch_bounds__(1024, 8) void scatterB_kernel(
        const int* __restrict__ rows, const int* __restrict__ cols,
        const float* __restrict__ vals,
        int* __restrict__ bucketCnt, i32x2* __restrict__ svcA) {
    __shared__ i32x2 lbuf[SB_EDGES];   // 50000 B
    __shared__ int   lhist[NB];        // counts (preserved)
    __shared__ int   sstart[NB];       // exclusive starts
    __shared__ int   lcur[NB];         // mutable scatter cursors
    const int tid  = threadIdx.x;
    const int base = blockIdx.x * SB_EDGES;

    if (tid < NB) lhist[tid] = 0;
    __syncthreads();

    // load 7 records/thread into NAMED registers + histogram
    // K=0..5 always in range (5*1024+1023 = 6143 < 6250); K=6 needs tid<106
    i32x2 r0, r1, r2, r3, r4, r5, r6;
    int   b0, b1, b2, b3, b4, b5, b6;
#define LOADREC(K, RK, BK)                                             \
    {                                                                  \
        int e = base + tid + (K) * 1024;                               \
        int rr = rows[e];                                              \
        BK = rr / RPB;                                                 \
        int local = rr - BK * RPB;                                     \
        RK[0] = (local << 17) | cols[e];                               \
        RK[1] = __float_as_int(vals[e]);                               \
        atomicAdd(&lhist[BK], 1);                                      \
    }
    LOADREC(0, r0, b0) LOADREC(1, r1, b1) LOADREC(2, r2, b2)
    LOADREC(3, r3, b3) LOADREC(4, r4, b4) LOADREC(5, r5, b5)
    if (tid < SB_EDGES - 6 * 1024) { LOADREC(6, r6, b6) }
#undef LOADREC
    __syncthreads();

    // single-wave scan over 512 bins: 8 consecutive bins per lane
    if (tid < 64) {
        const int bb = tid * 8;
        int run = 0;
#pragma unroll
        for (int j = 0; j < 8; ++j) run += lhist[bb + j];
        int s = run;
#pragma unroll
        for (int d = 1; d < 64; d <<= 1) {
            int t2 = __shfl_up(s, d, 64);
            if (tid >= d) s += t2;
        }
        int ex = s - run;              // exclusive prefix of this 8-bin group
#pragma unroll
        for (int j = 0; j < 8; ++j) {
            sstart[bb + j] = ex;
            lcur[bb + j]   = ex;
            ex += lhist[bb + j];
        }
    }
    __syncthreads();

    // scatter registers into bucket-sorted lbuf
    lbuf[atomicAdd(&lcur[b0], 1)] = r0;
    lbuf[atomicAdd(&lcur[b1], 1)] = r1;
    lbuf[atomicAdd(&lcur[b2], 1)] = r2;
    lbuf[atomicAdd(&lcur[b3], 1)] = r3;
    lbuf[atomicAdd(&lcur[b4], 1)] = r4;
    lbuf[atomicAdd(&lcur[b5], 1)] = r5;
    if (tid < SB_EDGES - 6 * 1024) lbuf[atomicAdd(&lcur[b6], 1)] = r6;
    __syncthreads();

    // drain: thread t < 512 owns bucket t; one far atomic, run copy (~12 recs)
    if (tid < NB) {
        int n = lhist[tid];
        if (n > 0) {
            int g = atomicAdd(&bucketCnt[tid], n);
            int s = sstart[tid];
            for (int i = 0; i < n; ++i)
                if (g + i < BCAP) svcA[(size_t)tid * BCAP + g + i] = lbuf[s + i];
        }
    }
}

// ---- K4: fused local sort (hist + single-wave shuffle scan) + segsum + relu
// EXACT R1 code (proven 64.5us, ~6.3 TB/s delivered = fabric ceiling).
__device__ __forceinline__ f32x2 bf2f(unsigned u) {
    f32x2 r;
    r[0] = __int_as_float(u << 16);
    r[1] = __int_as_float(u & 0xffff0000u);
    return r;
}

__global__ __launch_bounds__(1024, 8) void sortsum_kernel(
        const __bf16* __restrict__ h, const int* __restrict__ bucketCnt,
        const i32x2* __restrict__ svcA, float* __restrict__ out) {
    __shared__ i32x2 lbuf[BCAP];     // 28 KB
    __shared__ int   lhist[256];
    __shared__ int   send[256];      // inclusive scan (row ends)
    __shared__ int   lcur[256];      // scatter cursors (row starts, mutated)
    const int b   = blockIdx.x;
    const int tid = threadIdx.x;
    const int n   = min(bucketCnt[b], BCAP);
    const i32x2* win = svcA + (size_t)b * BCAP;

    if (tid < 256) lhist[tid] = 0;
    __syncthreads();

    // load window into registers (<=4 recs/thread) + LDS histogram
    i32x2 rec0, rec1, rec2, rec3;
    const int i0 = tid, i1 = tid + 1024, i2 = tid + 2048, i3 = tid + 3072;
    if (i0 < n) { rec0 = win[i0]; atomicAdd(&lhist[((unsigned)rec0[0]) >> 17], 1); }
    if (i1 < n) { rec1 = win[i1]; atomicAdd(&lhist[((unsigned)rec1[0]) >> 17], 1); }
    if (i2 < n) { rec2 = win[i2]; atomicAdd(&lhist[((unsigned)rec2[0]) >> 17], 1); }
    if (i3 < n) { rec3 = win[i3]; atomicAdd(&lhist[((unsigned)rec3[0]) >> 17], 1); }
    __syncthreads();

    // single-wave scan: wave 0, 4 consecutive bins per lane + shuffle scan
    if (tid < 64) {
        int b0 = lhist[tid * 4 + 0], b1 = lhist[tid * 4 + 1];
        int b2 = lhist[tid * 4 + 2], b3 = lhist[tid * 4 + 3];
        int p0 = b0, p1 = p0 + b1, p2 = p1 + b2, p3 = p2 + b3;
        int s = p3;
#pragma unroll
        for (int d = 1; d < 64; d <<= 1) {
            int t2 = __shfl_up(s, d, 64);
            if (tid >= d) s += t2;
        }
        int ex = s - p3;                 // exclusive prefix of this 4-bin group
        send[tid * 4 + 0] = ex + p0;
        send[tid * 4 + 1] = ex + p1;
        send[tid * 4 + 2] = ex + p2;
        send[tid * 4 + 3] = ex + p3;
        lcur[tid * 4 + 0] = ex;
        lcur[tid * 4 + 1] = ex + p0;
        lcur[tid * 4 + 2] = ex + p1;
        lcur[tid * 4 + 3] = ex + p2;
    }
    __syncthreads();

    // scatter registers into row-sorted LDS
    if (i0 < n) { int rl = ((unsigned)rec0[0]) >> 17; lbuf[atomicAdd(&lcur[rl], 1)] = rec0; }
    if (i1 < n) { int rl = ((unsigned)rec1[0]) >> 17; lbuf[atomicAdd(&lcur[rl], 1)] = rec1; }
    if (i2 < n) { int rl = ((unsigned)rec2[0]) >> 17; lbuf[atomicAdd(&lcur[rl], 1)] = rec2; }
    if (i3 < n) { int rl = ((unsigned)rec3[0]) >> 17; lbuf[atomicAdd(&lcur[rl], 1)] = rec3; }
    __syncthreads();

    // per-wave register-accumulator segsum, 8-deep gather pipeline
    const int wave = tid >> 6;
    const int lane = tid & 63;
    const char* hb = (const char*)h;
    const unsigned lo4 = (unsigned)lane * 4u;
    for (int rl = wave; rl < RPB; rl += 16) {
        int gr = b * RPB + rl;
        if (gr >= N_NODES) break;
        int s = rl ? send[rl - 1] : 0;
        int e = send[rl];

        f32x2 acc0 = (f32x2)(0.0f), acc1 = (f32x2)(0.0f);
        f32x2 acc2 = (f32x2)(0.0f), acc3 = (f32x2)(0.0f);
        int i = s;
        for (; i + 7 < e; i += 8) {
            i32x2 r0 = lbuf[i],     r1 = lbuf[i + 1], r2 = lbuf[i + 2], r3 = lbuf[i + 3];
            i32x2 r4 = lbuf[i + 4], r5 = lbuf[i + 5], r6 = lbuf[i + 6], r7 = lbuf[i + 7];
            unsigned o0 = (((unsigned)r0[0] & 0x1FFFFu) << 8) + lo4;
            unsigned o1 = (((unsigned)r1[0] & 0x1FFFFu) << 8) + lo4;
            unsigned o2 = (((unsigned)r2[0] & 0x1FFFFu) << 8) + lo4;
            unsigned o3 = (((unsigned)r3[0] & 0x1FFFFu) << 8) + lo4;
            unsigned o4 = (((unsigned)r4[0] & 0x1FFFFu) << 8) + lo4;
            unsigned o5 = (((unsigned)r5[0] & 0x1FFFFu) << 8) + lo4;
            unsigned o6 = (((unsigned)r6[0] & 0x1FFFFu) << 8) + lo4;
            unsigned o7 = (((unsigned)r7[0] & 0x1FFFFu) << 8) + lo4;
            unsigned u0 = *(const unsigned*)(hb + o0);
            unsigned u1 = *(const unsigned*)(hb + o1);
            unsigned u2 = *(const unsigned*)(hb + o2);
            unsigned u3 = *(const unsigned*)(hb + o3);
            unsigned u4 = *(const unsigned*)(hb + o4);
            unsigned u5 = *(const unsigned*)(hb + o5);
            unsigned u6 = *(const unsigned*)(hb + o6);
            unsigned u7 = *(const unsigned*)(hb + o7);
            acc0 += bf2f(u0) * __int_as_float(r0[1]);
            acc1 += bf2f(u1) * __int_as_float(r1[1]);
            acc2 += bf2f(u2) * __int_as_float(r2[1]);
            acc3 += bf2f(u3) * __int_as_float(r3[1]);
            acc0 += bf2f(u4) * __int_as_float(r4[1]);
            acc1 += bf2f(u5) * __int_as_float(r5[1]);
            acc2 += bf2f(u6) * __int_as_float(r6[1]);
            acc3 += bf2f(u7) * __int_as_float(r7[1]);
        }
        for (; i + 3 < e; i += 4) {
            i32x2 r0 = lbuf[i], r1 = lbuf[i + 1], r2 = lbuf[i + 2], r3 = lbuf[i + 3];
            unsigned o0 = (((unsigned)r0[0] & 0x1FFFFu) << 8) + lo4;
            unsigned o1 = (((unsigned)r1[0] & 0x1FFFFu) << 8) + lo4;
            unsigned o2 = (((unsigned)r2[0] & 0x1FFFFu) << 8) + lo4;
            unsigned o3 = (((unsigned)r3[0] & 0x1FFFFu) << 8) + lo4;
            unsigned u0 = *(const unsigned*)(hb + o0);
            unsigned u1 = *(const unsigned*)(hb + o1);
            unsigned u2 = *(const unsigned*)(hb + o2);
            unsigned u3 = *(const unsigned*)(hb + o3);
            acc0 += bf2f(u0) * __int_as_float(r0[1]);
            acc1 += bf2f(u1) * __int_as_float(r1[1]);
            acc2 += bf2f(u2) * __int_as_float(r2[1]);
            acc3 += bf2f(u3) * __int_as_float(r3[1]);
        }
        for (; i < e; ++i) {
            i32x2 r0 = lbuf[i];
            unsigned o0 = (((unsigned)r0[0] & 0x1FFFFu) << 8) + lo4;
            unsigned u0 = *(const unsigned*)(hb + o0);
            acc0 += bf2f(u0) * __int_as_float(r0[1]);
        }

        f32x2 t01 = acc0 + acc1, t23 = acc2 + acc3;
        f32x2 tt = t01 + t23;
        f32x2 o;
        o[0] = fmaxf(tt[0], 0.0f);
        o[1] = fmaxf(tt[1], 0.0f);
        __builtin_nontemporal_store(o, (f32x2*)(out + (size_t)gr * D + lane * 2));
    }
}

extern "C" void kernel_launch(void* const* d_in, const int* in_sizes, int n_in,
                              void* d_out, int out_size, void* d_ws, size_t ws_size,
                              hipStream_t stream) {
    const float* x    = (const float*)d_in[0];
    const float* w    = (const float*)d_in[1];
    const float* vals = (const float*)d_in[2];
    const int*   rows = (const int*)d_in[3];
    const int*   cols = (const int*)d_in[4];
    float*       out  = (float*)d_out;

    // ---- workspace (~40.3 MB) ----
    char* p = (char*)d_ws;
    __bf16* h         = (__bf16*)p;  p += (size_t)N_NODES * D * 2;          // 25.6 MB
    __bf16* WT        = (__bf16*)p;  p += (size_t)D * D * 2;                // 32 KB
    int*    bucketCnt = (int*)p;     p += 4096;                             // NB ints
    i32x2*  svcA      = (i32x2*)p;   p += (size_t)NB * BCAP * 8;            // 14.7 MB

    prep_kernel<<<64, 256, 0, stream>>>(w, WT, bucketCnt);
    gemm_kernel<<<(N_TILES + 3) / 4, 256, 0, stream>>>(x, WT, h);
    scatterB_kernel<<<SB_BLKS, 1024, 0, stream>>>(rows, cols, vals, bucketCnt, svcA);
    sortsum_kernel<<<NB, 1024, 0, stream>>>(h, bucketCnt, svcA, out);
}